// Round 2
// baseline (2017.132 us; speedup 1.0000x reference)
//
#include <hip/hip_runtime.h>
#include <cstdint>
#include <cstddef>

constexpr int Lc = 2, Ec = 8, Hc = 1024, Ic = 2048, Tc = 2048;

typedef __bf16 bf16x8 __attribute__((ext_vector_type(8)));
typedef float f32x4 __attribute__((ext_vector_type(4)));

__device__ __forceinline__ unsigned short f2bf(float f) {
  unsigned u = __builtin_bit_cast(unsigned, f);
  u = (u + 0x7fffu + ((u >> 16) & 1u)) >> 16;
  return (unsigned short)u;
}
__device__ __forceinline__ float bf2f(unsigned short h) {
  unsigned u = (unsigned)h << 16;
  return __builtin_bit_cast(float, u);
}
__device__ __forceinline__ bf16x8 ldfrag(const unsigned short* p) {
  return __builtin_bit_cast(bf16x8, *(const uint4*)p);
}
// async global->LDS, 16B per lane, LDS dest = uniform base + lane*16 (linear)
__device__ __forceinline__ void gl2lds(const unsigned short* g, void* lds) {
  __builtin_amdgcn_global_load_lds(
      (const __attribute__((address_space(1))) void*)g,
      (__attribute__((address_space(3))) void*)lds, 16, 0, 0);
}

// ---------------- router: logits[t][e] = sum_h x[t][h] * rw[h][e] (fp32) ----------------
__global__ void router_kernel(const float* __restrict__ x, const float* __restrict__ rw,
                              float* __restrict__ logits) {
  const int t = blockIdx.x;
  const int tid = threadIdx.x;
  float acc[Ec];
#pragma unroll
  for (int e = 0; e < Ec; ++e) acc[e] = 0.f;
  const float* xr = x + (size_t)t * Hc;
  for (int h = tid; h < Hc; h += 256) {
    const float xv = xr[h];
    const float* w = rw + (size_t)h * Ec;
#pragma unroll
    for (int e = 0; e < Ec; ++e) acc[e] += xv * w[e];
  }
  __shared__ float red[256][Ec];
#pragma unroll
  for (int e = 0; e < Ec; ++e) red[tid][e] = acc[e];
  __syncthreads();
  for (int s = 128; s > 0; s >>= 1) {
    if (tid < s) {
#pragma unroll
      for (int e = 0; e < Ec; ++e) red[tid][e] += red[tid + s][e];
    }
    __syncthreads();
  }
  if (tid < Ec) logits[(size_t)t * Ec + tid] = red[0][tid];
}

// ---------------- top-2 + normalized weights + per-expert append ----------------
__global__ void topk_kernel(const float* __restrict__ logits, int* __restrict__ cnt,
                            int* __restrict__ tokList, float* __restrict__ wList) {
  const int t = blockIdx.x * blockDim.x + threadIdx.x;
  if (t >= Tc) return;
  float l[Ec];
#pragma unroll
  for (int e = 0; e < Ec; ++e) l[e] = logits[(size_t)t * Ec + e];
  float b0 = -3.4e38f, b1 = -3.4e38f;
  int i0 = 0, i1 = 0;
#pragma unroll
  for (int e = 0; e < Ec; ++e) {
    if (l[e] > b0) { b1 = b0; i1 = i0; b0 = l[e]; i0 = e; }
    else if (l[e] > b1) { b1 = l[e]; i1 = e; }
  }
  const float w0 = 1.f / (1.f + expf(b1 - b0));
  const float w1 = 1.f - w0;
  int p0 = atomicAdd(&cnt[i0], 1);
  tokList[i0 * Tc + p0] = t;
  wList[i0 * Tc + p0] = w0;
  int p1 = atomicAdd(&cnt[i1], 1);
  tokList[i1 * Tc + p1] = t;
  wList[i1 * Tc + p1] = w1;
}

__global__ void offsets_kernel(const int* __restrict__ cnt, int* __restrict__ off) {
  if (threadIdx.x == 0) {
    int s = 0;
    for (int e = 0; e < Ec; ++e) { off[e] = s; s += cnt[e]; }
  }
}

// ---------------- fp32 -> (hi,lo) bf16 split for activations ----------------
__global__ void convert_kernel(const float* __restrict__ x, unsigned short* __restrict__ xh,
                               unsigned short* __restrict__ xl) {
  const int i = blockIdx.x * 256 + threadIdx.x;
  const float v = x[i];
  const unsigned short h = f2bf(v);
  xh[i] = h;
  xl[i] = f2bf(v - bf2f(h));
}

// ---------------- weight transpose+convert: fp32 [E][K][N] -> bf16 hi(/lo) [E][N][K] ----------------
template <bool SPLIT>
__global__ __launch_bounds__(256) void wconv_kernel(const float* __restrict__ src,
                                                    unsigned short* __restrict__ dh,
                                                    unsigned short* __restrict__ dl,
                                                    int K, int N) {
  const int e = blockIdx.z;
  const int n0 = blockIdx.x * 64;
  const int k0 = blockIdx.y * 64;
  src += (size_t)e * K * N;
  dh += (size_t)e * N * K;
  if constexpr (SPLIT) dl += (size_t)e * N * K;

  __shared__ unsigned short lh[64][66];
  __shared__ unsigned short ll[SPLIT ? 64 : 1][66];
  const int tid = threadIdx.x;

  {
    const int r = tid >> 2, cg = (tid & 3) * 16;
    const float* sp = src + (size_t)(k0 + r) * N + n0 + cg;
#pragma unroll
    for (int i = 0; i < 16; i += 4) {
      const float4 v = *(const float4*)(sp + i);
      const float f[4] = {v.x, v.y, v.z, v.w};
#pragma unroll
      for (int j = 0; j < 4; ++j) {
        const unsigned short h = f2bf(f[j]);
        lh[r][cg + i + j] = h;
        if constexpr (SPLIT) ll[r][cg + i + j] = f2bf(f[j] - bf2f(h));
      }
    }
  }
  __syncthreads();
  {
    const int nr = tid >> 2, kg = (tid & 3) * 16;
    union { unsigned short s[16]; uint4 u[2]; } oh, ol;
#pragma unroll
    for (int i = 0; i < 16; ++i) {
      oh.s[i] = lh[kg + i][nr];
      if constexpr (SPLIT) ol.s[i] = ll[kg + i][nr];
    }
    unsigned short* dp = dh + (size_t)(n0 + nr) * K + k0 + kg;
    *(uint4*)dp = oh.u[0];
    *(uint4*)(dp + 8) = oh.u[1];
    if constexpr (SPLIT) {
      unsigned short* dq = dl + (size_t)(n0 + nr) * K + k0 + kg;
      *(uint4*)dq = ol.u[0];
      *(uint4*)(dq + 8) = ol.u[1];
    }
  }
}

// ---------------- gate_up GEMM: BM=128, BN=64(g)+64(u), BK=32, frag-major LDS ----------------
// LDS layout: s[q][row][8] bf16 (q = k-quad 0..3). ds_read_b128 at (q*ROWS+row)*16B is
// contiguous per 16-lane group -> conflict-free. global_load_lds dest is linear; the
// "layout transform" lives in the per-lane GLOBAL source address (guide rule 21 / m173).
template <bool SPLIT>
__global__ __launch_bounds__(256) void gateup_kernel(
    const unsigned short* __restrict__ xh, const unsigned short* __restrict__ xl,
    const unsigned short* __restrict__ gwTh, const unsigned short* __restrict__ gwTl,
    const int* __restrict__ cnt, const int* __restrict__ off,
    const int* __restrict__ tokList, unsigned short* __restrict__ actH,
    unsigned short* __restrict__ actL) {
  const int e = blockIdx.z;
  const int M = cnt[e];
  const int m0 = blockIdx.x * 128;
  if (m0 >= M) return;
  const int n0 = blockIdx.y * 64;
  const int tid = threadIdx.x;
  const int wv = tid >> 6;
  const int l64 = tid & 63;
  const int q = l64 >> 4;
  const int mr = l64 & 15;
  const int nc = wv * 16 + mr;

  __shared__ __align__(16) unsigned short sAh[4 * 128 * 8];                 // 8 KB
  __shared__ __align__(16) unsigned short sAl[SPLIT ? 4 * 128 * 8 : 8];
  __shared__ __align__(16) unsigned short sBgh[4 * 64 * 8];                 // 4 KB
  __shared__ __align__(16) unsigned short sBgl[SPLIT ? 4 * 64 * 8 : 8];
  __shared__ __align__(16) unsigned short sBuh[4 * 64 * 8];
  __shared__ __align__(16) unsigned short sBul[SPLIT ? 4 * 64 * 8 : 8];

  // per-lane gathered A row bases (rows l64 and 64+l64 of this m-tile)
  int r0 = m0 + l64;      if (r0 >= M) r0 = M - 1;
  int r1 = m0 + 64 + l64; if (r1 >= M) r1 = M - 1;
  const size_t a0 = (size_t)tokList[e * Tc + r0] * Hc + wv * 8;
  const size_t a1 = (size_t)tokList[e * Tc + r1] * Hc + wv * 8;
  const size_t bg = ((size_t)e * 2 * Ic + n0 + l64) * Hc + wv * 8;
  const size_t bu = bg + (size_t)Ic * Hc;

  char* dA  = (char*)sAh + wv * 2048;   // wave wv stages q=wv slice (2 row-halves)
  char* dAl = (char*)sAl + wv * 2048;
  char* dBg = (char*)sBgh + wv * 1024;
  char* dBgl = (char*)sBgl + wv * 1024;
  char* dBu = (char*)sBuh + wv * 1024;
  char* dBul = (char*)sBul + wv * 1024;

  f32x4 accg[8], accu[8];
#pragma unroll
  for (int i = 0; i < 8; ++i) {
    accg[i] = f32x4{0.f, 0.f, 0.f, 0.f};
    accu[i] = f32x4{0.f, 0.f, 0.f, 0.f};
  }

  for (int k0 = 0; k0 < Hc; k0 += 32) {
    __syncthreads();
    gl2lds(xh + a0 + k0, dA);
    gl2lds(xh + a1 + k0, dA + 1024);
    gl2lds(gwTh + bg + k0, dBg);
    gl2lds(gwTh + bu + k0, dBu);
    if constexpr (SPLIT) {
      gl2lds(xl + a0 + k0, dAl);
      gl2lds(xl + a1 + k0, dAl + 1024);
      gl2lds(gwTl + bg + k0, dBgl);
      gl2lds(gwTl + bu + k0, dBul);
    }
    __syncthreads();  // compiler drains vmcnt(0) here -> staged data visible

    const bf16x8 bghf = ldfrag(&sBgh[(q * 64 + nc) * 8]);
    const bf16x8 buhf = ldfrag(&sBuh[(q * 64 + nc) * 8]);
    bf16x8 bglf, bulf;
    if constexpr (SPLIT) {
      bglf = ldfrag(&sBgl[(q * 64 + nc) * 8]);
      bulf = ldfrag(&sBul[(q * 64 + nc) * 8]);
    }
#pragma unroll
    for (int mt = 0; mt < 8; ++mt) {
      const bf16x8 ah = ldfrag(&sAh[(q * 128 + mt * 16 + mr) * 8]);
      accg[mt] = __builtin_amdgcn_mfma_f32_16x16x32_bf16(ah, bghf, accg[mt], 0, 0, 0);
      accu[mt] = __builtin_amdgcn_mfma_f32_16x16x32_bf16(ah, buhf, accu[mt], 0, 0, 0);
      if constexpr (SPLIT) {
        const bf16x8 alr = ldfrag(&sAl[(q * 128 + mt * 16 + mr) * 8]);
        accg[mt] = __builtin_amdgcn_mfma_f32_16x16x32_bf16(ah, bglf, accg[mt], 0, 0, 0);
        accg[mt] = __builtin_amdgcn_mfma_f32_16x16x32_bf16(alr, bghf, accg[mt], 0, 0, 0);
        accu[mt] = __builtin_amdgcn_mfma_f32_16x16x32_bf16(ah, bulf, accu[mt], 0, 0, 0);
        accu[mt] = __builtin_amdgcn_mfma_f32_16x16x32_bf16(alr, buhf, accu[mt], 0, 0, 0);
      }
    }
  }

  const int valid = M - m0;
  const int rowbase = off[e] + m0;
#pragma unroll
  for (int mt = 0; mt < 8; ++mt) {
#pragma unroll
    for (int r = 0; r < 4; ++r) {
      const int row = mt * 16 + q * 4 + r;  // C/D: row=(lane>>4)*4+reg, col=lane&15 (m89)
      if (row < valid) {
        const float g = accg[mt][r];
        const float u = accu[mt][r];
        const float a = (g / (1.f + expf(-g))) * u;
        const size_t idx = (size_t)(rowbase + row) * Ic + (n0 + nc);
        const unsigned short h = f2bf(a);
        actH[idx] = h;
        if constexpr (SPLIT) actL[idx] = f2bf(a - bf2f(h));
      }
    }
  }
}

// ---------------- down GEMM: BM=128, BN=64, BK=32, frag-major LDS ----------------
template <bool SPLIT>
__global__ __launch_bounds__(256) void down_kernel(
    const unsigned short* __restrict__ actH, const unsigned short* __restrict__ actL,
    const unsigned short* __restrict__ dwTh, const unsigned short* __restrict__ dwTl,
    const int* __restrict__ cnt, const int* __restrict__ off,
    const int* __restrict__ tokList, const float* __restrict__ wList,
    float* __restrict__ out) {
  const int e = blockIdx.z;
  const int M = cnt[e];
  const int m0 = blockIdx.x * 128;
  if (m0 >= M) return;
  const int n0 = blockIdx.y * 64;
  const int tid = threadIdx.x;
  const int wv = tid >> 6;
  const int l64 = tid & 63;
  const int q = l64 >> 4;
  const int mr = l64 & 15;
  const int nc = wv * 16 + mr;

  __shared__ __align__(16) unsigned short sAh[4 * 128 * 8];
  __shared__ __align__(16) unsigned short sAl[SPLIT ? 4 * 128 * 8 : 8];
  __shared__ __align__(16) unsigned short sBh[4 * 64 * 8];
  __shared__ __align__(16) unsigned short sBl[SPLIT ? 4 * 64 * 8 : 8];
  __shared__ int sTok[128];
  __shared__ float sW[128];

  if (tid < 128) {
    int r = m0 + tid;
    int rc = r < M ? r : M - 1;
    sTok[tid] = tokList[e * Tc + rc];
    sW[tid] = wList[e * Tc + rc];
  }

  int r0 = m0 + l64;      if (r0 >= M) r0 = M - 1;
  int r1 = m0 + 64 + l64; if (r1 >= M) r1 = M - 1;
  const size_t a0 = (size_t)(off[e] + r0) * Ic + wv * 8;
  const size_t a1 = (size_t)(off[e] + r1) * Ic + wv * 8;
  const size_t bb = ((size_t)e * Hc + n0 + l64) * Ic + wv * 8;

  char* dA  = (char*)sAh + wv * 2048;
  char* dAl = (char*)sAl + wv * 2048;
  char* dB  = (char*)sBh + wv * 1024;
  char* dBl = (char*)sBl + wv * 1024;

  f32x4 acc[8];
#pragma unroll
  for (int i = 0; i < 8; ++i) acc[i] = f32x4{0.f, 0.f, 0.f, 0.f};

  for (int k0 = 0; k0 < Ic; k0 += 32) {
    __syncthreads();  // also covers initial sTok/sW visibility
    gl2lds(actH + a0 + k0, dA);
    gl2lds(actH + a1 + k0, dA + 1024);
    gl2lds(dwTh + bb + k0, dB);
    if constexpr (SPLIT) {
      gl2lds(actL + a0 + k0, dAl);
      gl2lds(actL + a1 + k0, dAl + 1024);
      gl2lds(dwTl + bb + k0, dBl);
    }
    __syncthreads();

    const bf16x8 bh = ldfrag(&sBh[(q * 64 + nc) * 8]);
    bf16x8 bl;
    if constexpr (SPLIT) bl = ldfrag(&sBl[(q * 64 + nc) * 8]);
#pragma unroll
    for (int mt = 0; mt < 8; ++mt) {
      const bf16x8 ah = ldfrag(&sAh[(q * 128 + mt * 16 + mr) * 8]);
      acc[mt] = __builtin_amdgcn_mfma_f32_16x16x32_bf16(ah, bh, acc[mt], 0, 0, 0);
      if constexpr (SPLIT) {
        const bf16x8 alr = ldfrag(&sAl[(q * 128 + mt * 16 + mr) * 8]);
        acc[mt] = __builtin_amdgcn_mfma_f32_16x16x32_bf16(ah, bl, acc[mt], 0, 0, 0);
        acc[mt] = __builtin_amdgcn_mfma_f32_16x16x32_bf16(alr, bh, acc[mt], 0, 0, 0);
      }
    }
  }

  const int valid = M - m0;
#pragma unroll
  for (int mt = 0; mt < 8; ++mt) {
#pragma unroll
    for (int r = 0; r < 4; ++r) {
      const int row = mt * 16 + q * 4 + r;
      if (row < valid) {
        atomicAdd(&out[(size_t)sTok[row] * Hc + (n0 + nc)], sW[row] * acc[mt][r]);
      }
    }
  }
}

// ---------------- host ----------------
extern "C" void kernel_launch(void* const* d_in, const int* in_sizes, int n_in, void* d_out,
                              int out_size, void* d_ws, size_t ws_size, hipStream_t stream) {
  const float* x_in = (const float*)d_in[0];
  const float* rw = (const float*)d_in[1];
  const float* guw = (const float*)d_in[2];
  const float* dnw = (const float*)d_in[3];
  float* out = (float*)d_out;
  float* logits_base = out + (size_t)Tc * Hc;

  uint8_t* w = (uint8_t*)d_ws;
  float* x1 = (float*)w;                    w += (size_t)Tc * Hc * 4;
  unsigned short* xh = (unsigned short*)w;  w += (size_t)Tc * Hc * 2;
  unsigned short* xl = (unsigned short*)w;  w += (size_t)Tc * Hc * 2;
  unsigned short* actH = (unsigned short*)w; w += (size_t)Tc * 2 * Ic * 2;
  unsigned short* actL = (unsigned short*)w; w += (size_t)Tc * 2 * Ic * 2;
  int* tokList = (int*)w;                   w += (size_t)Ec * Tc * 4;
  float* wList = (float*)w;                 w += (size_t)Ec * Tc * 4;
  int* cnt0 = (int*)w;                      w += 64;
  int* cnt1 = (int*)w;                      w += 64;
  int* off = (int*)w;                       w += 64;
  unsigned short* wTh = (unsigned short*)w; w += (size_t)Ec * 2 * Ic * Hc * 2;
  unsigned short* wTl = (unsigned short*)w; w += (size_t)Ec * 2 * Ic * Hc * 2;

  hipMemsetAsync(cnt0, 0, 192, stream);
  hipMemsetAsync(x1, 0, (size_t)Tc * Hc * 4, stream);
  hipMemsetAsync(out, 0, (size_t)Tc * Hc * 4, stream);

  // ---- layer 0 (split-bf16 precision; protects layer-1 routing) ----
  router_kernel<<<Tc, 256, 0, stream>>>(x_in, rw, logits_base);
  topk_kernel<<<Tc / 256, 256, 0, stream>>>(logits_base, cnt0, tokList, wList);
  offsets_kernel<<<1, 64, 0, stream>>>(cnt0, off);
  convert_kernel<<<(Tc * Hc) / 256, 256, 0, stream>>>(x_in, xh, xl);
  wconv_kernel<true><<<dim3(2 * Ic / 64, Hc / 64, Ec), 256, 0, stream>>>(guw, wTh, wTl, Hc, 2 * Ic);
  gateup_kernel<true><<<dim3(Tc / 128, Ic / 64, Ec), 256, 0, stream>>>(xh, xl, wTh, wTl, cnt0, off,
                                                                       tokList, actH, actL);
  wconv_kernel<true><<<dim3(Hc / 64, Ic / 64, Ec), 256, 0, stream>>>(dnw, wTh, wTl, Ic, Hc);
  down_kernel<true><<<dim3(Tc / 128, Hc / 64, Ec), 256, 0, stream>>>(actH, actL, wTh, wTl, cnt0,
                                                                     off, tokList, wList, x1);

  // ---- layer 1 (plain bf16) ----
  const float* rw1 = rw + (size_t)Hc * Ec;
  const float* guw1 = guw + (size_t)Ec * Hc * 2 * Ic;
  const float* dnw1 = dnw + (size_t)Ec * Ic * Hc;
  router_kernel<<<Tc, 256, 0, stream>>>(x1, rw1, logits_base + (size_t)Tc * Ec);
  topk_kernel<<<Tc / 256, 256, 0, stream>>>(logits_base + (size_t)Tc * Ec, cnt1, tokList, wList);
  offsets_kernel<<<1, 64, 0, stream>>>(cnt1, off);
  convert_kernel<<<(Tc * Hc) / 256, 256, 0, stream>>>(x1, xh, xl);
  wconv_kernel<false><<<dim3(2 * Ic / 64, Hc / 64, Ec), 256, 0, stream>>>(guw1, wTh, wTl, Hc, 2 * Ic);
  gateup_kernel<false><<<dim3(Tc / 128, Ic / 64, Ec), 256, 0, stream>>>(xh, xl, wTh, wTl, cnt1, off,
                                                                        tokList, actH, actL);
  wconv_kernel<false><<<dim3(Hc / 64, Ic / 64, Ec), 256, 0, stream>>>(dnw1, wTh, wTl, Ic, Hc);
  down_kernel<false><<<dim3(Tc / 128, Hc / 64, Ec), 256, 0, stream>>>(actH, actL, wTh, wTl, cnt1,
                                                                      off, tokList, wList, out);
}

// Round 3
// 1538.398 us; speedup vs baseline: 1.3112x; 1.3112x over previous
//
#include <hip/hip_runtime.h>
#include <cstdint>
#include <cstddef>

constexpr int Lc = 2, Ec = 8, Hc = 1024, Ic = 2048, Tc = 2048;

typedef __bf16 bf16x8 __attribute__((ext_vector_type(8)));
typedef float f32x4 __attribute__((ext_vector_type(4)));

__device__ __forceinline__ unsigned short f2bf(float f) {
  unsigned u = __builtin_bit_cast(unsigned, f);
  u = (u + 0x7fffu + ((u >> 16) & 1u)) >> 16;
  return (unsigned short)u;
}
__device__ __forceinline__ float bf2f(unsigned short h) {
  unsigned u = (unsigned)h << 16;
  return __builtin_bit_cast(float, u);
}
__device__ __forceinline__ bf16x8 ldfrag(const unsigned short* p) {
  return __builtin_bit_cast(bf16x8, *(const uint4*)p);
}
// async global->LDS, 16B/lane; LDS dest = wave-uniform base + lane*16 (linear)
__device__ __forceinline__ void gl2lds(const unsigned short* g, void* lds) {
  __builtin_amdgcn_global_load_lds(
      (const __attribute__((address_space(1))) void*)g,
      (__attribute__((address_space(3))) void*)lds, 16, 0, 0);
}

// ---------------- router ----------------
__global__ void router_kernel(const float* __restrict__ x, const float* __restrict__ rw,
                              float* __restrict__ logits) {
  const int t = blockIdx.x;
  const int tid = threadIdx.x;
  float acc[Ec];
#pragma unroll
  for (int e = 0; e < Ec; ++e) acc[e] = 0.f;
  const float* xr = x + (size_t)t * Hc;
  for (int h = tid; h < Hc; h += 256) {
    const float xv = xr[h];
    const float* w = rw + (size_t)h * Ec;
#pragma unroll
    for (int e = 0; e < Ec; ++e) acc[e] += xv * w[e];
  }
  __shared__ float red[256][Ec];
#pragma unroll
  for (int e = 0; e < Ec; ++e) red[tid][e] = acc[e];
  __syncthreads();
  for (int s = 128; s > 0; s >>= 1) {
    if (tid < s) {
#pragma unroll
      for (int e = 0; e < Ec; ++e) red[tid][e] += red[tid + s][e];
    }
    __syncthreads();
  }
  if (tid < Ec) logits[(size_t)t * Ec + tid] = red[0][tid];
}

// ---------------- top-2 ----------------
__global__ void topk_kernel(const float* __restrict__ logits, int* __restrict__ cnt,
                            int* __restrict__ tokList, float* __restrict__ wList) {
  const int t = blockIdx.x * blockDim.x + threadIdx.x;
  if (t >= Tc) return;
  float l[Ec];
#pragma unroll
  for (int e = 0; e < Ec; ++e) l[e] = logits[(size_t)t * Ec + e];
  float b0 = -3.4e38f, b1 = -3.4e38f;
  int i0 = 0, i1 = 0;
#pragma unroll
  for (int e = 0; e < Ec; ++e) {
    if (l[e] > b0) { b1 = b0; i1 = i0; b0 = l[e]; i0 = e; }
    else if (l[e] > b1) { b1 = l[e]; i1 = e; }
  }
  const float w0 = 1.f / (1.f + expf(b1 - b0));
  const float w1 = 1.f - w0;
  int p0 = atomicAdd(&cnt[i0], 1);
  tokList[i0 * Tc + p0] = t;
  wList[i0 * Tc + p0] = w0;
  int p1 = atomicAdd(&cnt[i1], 1);
  tokList[i1 * Tc + p1] = t;
  wList[i1 * Tc + p1] = w1;
}

__global__ void offsets_kernel(const int* __restrict__ cnt, int* __restrict__ off) {
  if (threadIdx.x == 0) {
    int s = 0;
    for (int e = 0; e < Ec; ++e) { off[e] = s; s += cnt[e]; }
  }
}

// ---------------- fp32 -> (hi,lo) bf16 split for activations ----------------
__global__ void convert_kernel(const float* __restrict__ x, unsigned short* __restrict__ xh,
                               unsigned short* __restrict__ xl) {
  const int i = blockIdx.x * 256 + threadIdx.x;
  const float v = x[i];
  const unsigned short h = f2bf(v);
  xh[i] = h;
  xl[i] = f2bf(v - bf2f(h));
}

// ---------------- weight convert into STAGED-TILE order ----------------
// fp32 [E][K][N]  ->  bf16 staged [e][nb=N/64][ks=K/32][q=4][n=64][j=8]
// chunk(e,nb,ks) = 2048 shorts = 4KB; element (q,n,j) = bf16(src[ks*32+q*8+j][nb*64+n]).
// A wave's gl2lds then reads 1KB CONTIGUOUS per (buffer, K-step).
template <bool SPLIT>
__global__ __launch_bounds__(256) void wconv_kernel(const float* __restrict__ src,
                                                    unsigned short* __restrict__ dh,
                                                    unsigned short* __restrict__ dl,
                                                    int K, int N) {
  const int e = blockIdx.z;
  const int n0 = blockIdx.x * 64;
  const int k0 = blockIdx.y * 64;
  const int NB = N >> 6, KS = K >> 5;
  src += (size_t)e * K * N;

  __shared__ unsigned short lh[64][66];
  __shared__ unsigned short ll[SPLIT ? 64 : 1][66];
  const int tid = threadIdx.x;

  {  // read 64x64 fp32 tile, coalesced along N
    const int r = tid >> 2, cg = (tid & 3) * 16;
    const float* sp = src + (size_t)(k0 + r) * N + n0 + cg;
#pragma unroll
    for (int i = 0; i < 16; i += 4) {
      const float4 v = *(const float4*)(sp + i);
      const float f[4] = {v.x, v.y, v.z, v.w};
#pragma unroll
      for (int j = 0; j < 4; ++j) {
        const unsigned short h = f2bf(f[j]);
        lh[r][cg + i + j] = h;
        if constexpr (SPLIT) ll[r][cg + i + j] = f2bf(f[j] - bf2f(h));
      }
    }
  }
  __syncthreads();
  {  // write staged: thread -> (ksl, q, n2..n2+1), 16 shorts contiguous
    const int ksl = tid >> 7, q = (tid >> 5) & 3, n2 = (tid & 31) * 2;
    const int kb = ksl * 32 + q * 8;
    union { unsigned short s[16]; uint4 u[2]; } oh, ol;
#pragma unroll
    for (int s = 0; s < 2; ++s)
#pragma unroll
      for (int i = 0; i < 8; ++i) {
        oh.s[s * 8 + i] = lh[kb + i][n2 + s];
        if constexpr (SPLIT) ol.s[s * 8 + i] = ll[kb + i][n2 + s];
      }
    const size_t cb =
        (((size_t)e * NB + (n0 >> 6)) * KS + (k0 >> 5) + ksl) * 2048 + q * 512 + n2 * 8;
    *(uint4*)(dh + cb) = oh.u[0];
    *(uint4*)(dh + cb + 8) = oh.u[1];
    if constexpr (SPLIT) {
      *(uint4*)(dl + cb) = ol.u[0];
      *(uint4*)(dl + cb + 8) = ol.u[1];
    }
  }
}

// ---------------- gate_up GEMM: BM=128, BN=64(g)+64(u), BK=32 ----------------
// B: staged chunks via gl2lds (coalesced 1KB/wave, frag-major, conflict-free reads).
// A: reg-staged into [128][40] padded row-major (2-way alias = free), next-K prefetch.
template <bool SPLIT>
__global__ __launch_bounds__(256) void gateup_kernel(
    const unsigned short* __restrict__ xh, const unsigned short* __restrict__ xl,
    const unsigned short* __restrict__ gwSh, const unsigned short* __restrict__ gwSl,
    const int* __restrict__ cnt, const int* __restrict__ off,
    const int* __restrict__ tokList, unsigned short* __restrict__ actH,
    unsigned short* __restrict__ actL) {
  const int e = blockIdx.z;
  const int M = cnt[e];
  const int m0 = blockIdx.x * 128;
  if (m0 >= M) return;
  const int nb = blockIdx.y;  // n0 = nb*64 within I
  const int tid = threadIdx.x;
  const int wv = tid >> 6, l64 = tid & 63;
  const int q = l64 >> 4, mr = l64 & 15;
  const int nc = wv * 16 + mr;

  __shared__ __align__(16) unsigned short sAh[128 * 40];
  __shared__ __align__(16) unsigned short sAl[SPLIT ? 128 * 40 : 8];
  __shared__ __align__(16) unsigned short sBgh[2048];
  __shared__ __align__(16) unsigned short sBgl[SPLIT ? 2048 : 8];
  __shared__ __align__(16) unsigned short sBuh[2048];
  __shared__ __align__(16) unsigned short sBul[SPLIT ? 2048 : 8];

  // staged-weight bases: [e][nb(64)][ks(32)] chunks of 2048 shorts; u at nb+32
  const size_t gBase = (((size_t)e * 64 + nb) * 32) * 2048 + tid * 8;
  const size_t uBase = (((size_t)e * 64 + nb + 32) * 32) * 2048 + tid * 8;
  char* dBg = (char*)sBgh + wv * 1024;
  char* dBu = (char*)sBuh + wv * 1024;
  char* dBgl = (char*)sBgl + wv * 1024;
  char* dBul = (char*)sBul + wv * 1024;

  // A: thread stages rows ar, ar+64 at k-seg ak
  const int ar = tid >> 2, ak = (tid & 3) * 8;
  int r0 = m0 + ar;      if (r0 >= M) r0 = M - 1;
  int r1 = m0 + 64 + ar; if (r1 >= M) r1 = M - 1;
  const size_t a0o = (size_t)tokList[e * Tc + r0] * Hc + ak;
  const size_t a1o = (size_t)tokList[e * Tc + r1] * Hc + ak;

  f32x4 accg[8], accu[8];
#pragma unroll
  for (int i = 0; i < 8; ++i) {
    accg[i] = f32x4{0.f, 0.f, 0.f, 0.f};
    accu[i] = f32x4{0.f, 0.f, 0.f, 0.f};
  }

  uint4 p0h = *(const uint4*)(xh + a0o);
  uint4 p1h = *(const uint4*)(xh + a1o);
  uint4 p0l, p1l;
  if constexpr (SPLIT) {
    p0l = *(const uint4*)(xl + a0o);
    p1l = *(const uint4*)(xl + a1o);
  }

  for (int ks = 0; ks < 32; ++ks) {
    __syncthreads();
    *(uint4*)&sAh[ar * 40 + ak] = p0h;
    *(uint4*)&sAh[(ar + 64) * 40 + ak] = p1h;
    if constexpr (SPLIT) {
      *(uint4*)&sAl[ar * 40 + ak] = p0l;
      *(uint4*)&sAl[(ar + 64) * 40 + ak] = p1l;
    }
    gl2lds(gwSh + gBase + (size_t)ks * 2048, dBg);
    gl2lds(gwSh + uBase + (size_t)ks * 2048, dBu);
    if constexpr (SPLIT) {
      gl2lds(gwSl + gBase + (size_t)ks * 2048, dBgl);
      gl2lds(gwSl + uBase + (size_t)ks * 2048, dBul);
    }
    if (ks < 31) {
      const int ko = (ks + 1) * 32;
      p0h = *(const uint4*)(xh + a0o + ko);
      p1h = *(const uint4*)(xh + a1o + ko);
      if constexpr (SPLIT) {
        p0l = *(const uint4*)(xl + a0o + ko);
        p1l = *(const uint4*)(xl + a1o + ko);
      }
    }
    __syncthreads();

    const bf16x8 bghf = ldfrag(&sBgh[(q * 64 + nc) * 8]);
    const bf16x8 buhf = ldfrag(&sBuh[(q * 64 + nc) * 8]);
    bf16x8 bglf, bulf;
    if constexpr (SPLIT) {
      bglf = ldfrag(&sBgl[(q * 64 + nc) * 8]);
      bulf = ldfrag(&sBul[(q * 64 + nc) * 8]);
    }
#pragma unroll
    for (int mt = 0; mt < 8; ++mt) {
      const bf16x8 ah = ldfrag(&sAh[(mt * 16 + mr) * 40 + q * 8]);
      accg[mt] = __builtin_amdgcn_mfma_f32_16x16x32_bf16(ah, bghf, accg[mt], 0, 0, 0);
      accu[mt] = __builtin_amdgcn_mfma_f32_16x16x32_bf16(ah, buhf, accu[mt], 0, 0, 0);
      if constexpr (SPLIT) {
        const bf16x8 alr = ldfrag(&sAl[(mt * 16 + mr) * 40 + q * 8]);
        accg[mt] = __builtin_amdgcn_mfma_f32_16x16x32_bf16(ah, bglf, accg[mt], 0, 0, 0);
        accg[mt] = __builtin_amdgcn_mfma_f32_16x16x32_bf16(alr, bghf, accg[mt], 0, 0, 0);
        accu[mt] = __builtin_amdgcn_mfma_f32_16x16x32_bf16(ah, bulf, accu[mt], 0, 0, 0);
        accu[mt] = __builtin_amdgcn_mfma_f32_16x16x32_bf16(alr, buhf, accu[mt], 0, 0, 0);
      }
    }
  }

  const int valid = M - m0;
  const int rowbase = off[e] + m0;
#pragma unroll
  for (int mt = 0; mt < 8; ++mt) {
#pragma unroll
    for (int r = 0; r < 4; ++r) {
      const int row = mt * 16 + q * 4 + r;  // C/D: row=(lane>>4)*4+reg, col=lane&15 (m89)
      if (row < valid) {
        const float g = accg[mt][r];
        const float u = accu[mt][r];
        const float a = (g / (1.f + expf(-g))) * u;
        const size_t idx = (size_t)(rowbase + row) * Ic + (nb * 64 + nc);
        const unsigned short h = f2bf(a);
        actH[idx] = h;
        if constexpr (SPLIT) actL[idx] = f2bf(a - bf2f(h));
      }
    }
  }
}

// ---------------- down GEMM: BM=128, BN=64, K=Ic ----------------
template <bool SPLIT>
__global__ __launch_bounds__(256) void down_kernel(
    const unsigned short* __restrict__ actH, const unsigned short* __restrict__ actL,
    const unsigned short* __restrict__ dwSh, const unsigned short* __restrict__ dwSl,
    const int* __restrict__ cnt, const int* __restrict__ off,
    const int* __restrict__ tokList, const float* __restrict__ wList,
    float* __restrict__ out) {
  const int e = blockIdx.z;
  const int M = cnt[e];
  const int m0 = blockIdx.x * 128;
  if (m0 >= M) return;
  const int nb = blockIdx.y;  // n0 = nb*64 within H
  const int tid = threadIdx.x;
  const int wv = tid >> 6, l64 = tid & 63;
  const int q = l64 >> 4, mr = l64 & 15;
  const int nc = wv * 16 + mr;

  __shared__ __align__(16) unsigned short sAh[128 * 40];
  __shared__ __align__(16) unsigned short sAl[SPLIT ? 128 * 40 : 8];
  __shared__ __align__(16) unsigned short sBh[2048];
  __shared__ __align__(16) unsigned short sBl[SPLIT ? 2048 : 8];
  __shared__ int sTok[128];
  __shared__ float sW[128];

  if (tid < 128) {
    int r = m0 + tid;
    int rc = r < M ? r : M - 1;
    sTok[tid] = tokList[e * Tc + rc];
    sW[tid] = wList[e * Tc + rc];
  }

  const size_t bBase = (((size_t)e * 16 + nb) * 64) * 2048 + tid * 8;
  char* dB = (char*)sBh + wv * 1024;
  char* dBl = (char*)sBl + wv * 1024;

  const int ar = tid >> 2, ak = (tid & 3) * 8;
  int r0 = m0 + ar;      if (r0 >= M) r0 = M - 1;
  int r1 = m0 + 64 + ar; if (r1 >= M) r1 = M - 1;
  const size_t a0o = (size_t)(off[e] + r0) * Ic + ak;
  const size_t a1o = (size_t)(off[e] + r1) * Ic + ak;

  f32x4 acc[8];
#pragma unroll
  for (int i = 0; i < 8; ++i) acc[i] = f32x4{0.f, 0.f, 0.f, 0.f};

  uint4 p0h = *(const uint4*)(actH + a0o);
  uint4 p1h = *(const uint4*)(actH + a1o);
  uint4 p0l, p1l;
  if constexpr (SPLIT) {
    p0l = *(const uint4*)(actL + a0o);
    p1l = *(const uint4*)(actL + a1o);
  }

  for (int ks = 0; ks < 64; ++ks) {
    __syncthreads();
    *(uint4*)&sAh[ar * 40 + ak] = p0h;
    *(uint4*)&sAh[(ar + 64) * 40 + ak] = p1h;
    if constexpr (SPLIT) {
      *(uint4*)&sAl[ar * 40 + ak] = p0l;
      *(uint4*)&sAl[(ar + 64) * 40 + ak] = p1l;
    }
    gl2lds(dwSh + bBase + (size_t)ks * 2048, dB);
    if constexpr (SPLIT) gl2lds(dwSl + bBase + (size_t)ks * 2048, dBl);
    if (ks < 63) {
      const int ko = (ks + 1) * 32;
      p0h = *(const uint4*)(actH + a0o + ko);
      p1h = *(const uint4*)(actH + a1o + ko);
      if constexpr (SPLIT) {
        p0l = *(const uint4*)(actL + a0o + ko);
        p1l = *(const uint4*)(actL + a1o + ko);
      }
    }
    __syncthreads();

    const bf16x8 bh = ldfrag(&sBh[(q * 64 + nc) * 8]);
    bf16x8 bl;
    if constexpr (SPLIT) bl = ldfrag(&sBl[(q * 64 + nc) * 8]);
#pragma unroll
    for (int mt = 0; mt < 8; ++mt) {
      const bf16x8 ah = ldfrag(&sAh[(mt * 16 + mr) * 40 + q * 8]);
      acc[mt] = __builtin_amdgcn_mfma_f32_16x16x32_bf16(ah, bh, acc[mt], 0, 0, 0);
      if constexpr (SPLIT) {
        const bf16x8 alr = ldfrag(&sAl[(mt * 16 + mr) * 40 + q * 8]);
        acc[mt] = __builtin_amdgcn_mfma_f32_16x16x32_bf16(ah, bl, acc[mt], 0, 0, 0);
        acc[mt] = __builtin_amdgcn_mfma_f32_16x16x32_bf16(alr, bh, acc[mt], 0, 0, 0);
      }
    }
  }

  const int valid = M - m0;
#pragma unroll
  for (int mt = 0; mt < 8; ++mt) {
#pragma unroll
    for (int r = 0; r < 4; ++r) {
      const int row = mt * 16 + q * 4 + r;
      if (row < valid) {
        atomicAdd(&out[(size_t)sTok[row] * Hc + (nb * 64 + nc)], sW[row] * acc[mt][r]);
      }
    }
  }
}

// ---------------- host ----------------
extern "C" void kernel_launch(void* const* d_in, const int* in_sizes, int n_in, void* d_out,
                              int out_size, void* d_ws, size_t ws_size, hipStream_t stream) {
  const float* x_in = (const float*)d_in[0];
  const float* rw = (const float*)d_in[1];
  const float* guw = (const float*)d_in[2];
  const float* dnw = (const float*)d_in[3];
  float* out = (float*)d_out;
  float* logits_base = out + (size_t)Tc * Hc;

  uint8_t* w = (uint8_t*)d_ws;
  float* x1 = (float*)w;                    w += (size_t)Tc * Hc * 4;
  unsigned short* xh = (unsigned short*)w;  w += (size_t)Tc * Hc * 2;
  unsigned short* xl = (unsigned short*)w;  w += (size_t)Tc * Hc * 2;
  unsigned short* actH = (unsigned short*)w; w += (size_t)Tc * 2 * Ic * 2;
  unsigned short* actL = (unsigned short*)w; w += (size_t)Tc * 2 * Ic * 2;
  int* tokList = (int*)w;                   w += (size_t)Ec * Tc * 4;
  float* wList = (float*)w;                 w += (size_t)Ec * Tc * 4;
  int* cnt0 = (int*)w;                      w += 64;
  int* cnt1 = (int*)w;                      w += 64;
  int* off = (int*)w;                       w += 64;
  unsigned short* wTh = (unsigned short*)w; w += (size_t)Ec * 2 * Ic * Hc * 2;
  unsigned short* wTl = (unsigned short*)w; w += (size_t)Ec * 2 * Ic * Hc * 2;

  hipMemsetAsync(cnt0, 0, 192, stream);
  hipMemsetAsync(x1, 0, (size_t)Tc * Hc * 4, stream);
  hipMemsetAsync(out, 0, (size_t)Tc * Hc * 4, stream);

  // ---- layer 0 (split-bf16 precision) ----
  router_kernel<<<Tc, 256, 0, stream>>>(x_in, rw, logits_base);
  topk_kernel<<<Tc / 256, 256, 0, stream>>>(logits_base, cnt0, tokList, wList);
  offsets_kernel<<<1, 64, 0, stream>>>(cnt0, off);
  convert_kernel<<<(Tc * Hc) / 256, 256, 0, stream>>>(x_in, xh, xl);
  wconv_kernel<true><<<dim3(2 * Ic / 64, Hc / 64, Ec), 256, 0, stream>>>(guw, wTh, wTl, Hc, 2 * Ic);
  gateup_kernel<true><<<dim3(Tc / 128, Ic / 64, Ec), 256, 0, stream>>>(xh, xl, wTh, wTl, cnt0, off,
                                                                       tokList, actH, actL);
  wconv_kernel<true><<<dim3(Hc / 64, Ic / 64, Ec), 256, 0, stream>>>(dnw, wTh, wTl, Ic, Hc);
  down_kernel<true><<<dim3(Tc / 128, Hc / 64, Ec), 256, 0, stream>>>(actH, actL, wTh, wTl, cnt0,
                                                                     off, tokList, wList, x1);

  // ---- layer 1 (plain bf16) ----
  const float* rw1 = rw + (size_t)Hc * Ec;
  const float* guw1 = guw + (size_t)Ec * Hc * 2 * Ic;
  const float* dnw1 = dnw + (size_t)Ec * Ic * Hc;
  router_kernel<<<Tc, 256, 0, stream>>>(x1, rw1, logits_base + (size_t)Tc * Ec);
  topk_kernel<<<Tc / 256, 256, 0, stream>>>(logits_base + (size_t)Tc * Ec, cnt1, tokList, wList);
  offsets_kernel<<<1, 64, 0, stream>>>(cnt1, off);
  convert_kernel<<<(Tc * Hc) / 256, 256, 0, stream>>>(x1, xh, xl);
  wconv_kernel<false><<<dim3(2 * Ic / 64, Hc / 64, Ec), 256, 0, stream>>>(guw1, wTh, wTl, Hc, 2 * Ic);
  gateup_kernel<false><<<dim3(Tc / 128, Ic / 64, Ec), 256, 0, stream>>>(xh, xl, wTh, wTl, cnt1, off,
                                                                        tokList, actH, actL);
  wconv_kernel<false><<<dim3(Hc / 64, Ic / 64, Ec), 256, 0, stream>>>(dnw1, wTh, wTl, Ic, Hc);
  down_kernel<false><<<dim3(Tc / 128, Hc / 64, Ec), 256, 0, stream>>>(actH, actL, wTh, wTl, cnt1,
                                                                      off, tokList, wList, out);
}

// Round 4
// 1022.232 us; speedup vs baseline: 1.9733x; 1.5049x over previous
//
#include <hip/hip_runtime.h>
#include <cstdint>
#include <cstddef>

constexpr int Lc = 2, Ec = 8, Hc = 1024, Ic = 2048, Tc = 2048;

typedef __bf16 bf16x8 __attribute__((ext_vector_type(8)));
typedef float f32x4 __attribute__((ext_vector_type(4)));

__device__ __forceinline__ unsigned short f2bf(float f) {
  unsigned u = __builtin_bit_cast(unsigned, f);
  u = (u + 0x7fffu + ((u >> 16) & 1u)) >> 16;
  return (unsigned short)u;
}
__device__ __forceinline__ float bf2f(unsigned short h) {
  unsigned u = (unsigned)h << 16;
  return __builtin_bit_cast(float, u);
}
__device__ __forceinline__ bf16x8 ldfrag(const unsigned short* p) {
  return __builtin_bit_cast(bf16x8, *(const uint4*)p);
}
// async global->LDS, 16B/lane; LDS dest = wave-uniform base + lane*16 (linear)
__device__ __forceinline__ void gl2lds(const unsigned short* g, void* lds) {
  __builtin_amdgcn_global_load_lds(
      (const __attribute__((address_space(1))) void*)g,
      (__attribute__((address_space(3))) void*)lds, 16, 0, 0);
}

// ---------------- router ----------------
__global__ void router_kernel(const float* __restrict__ x, const float* __restrict__ rw,
                              float* __restrict__ logits) {
  const int t = blockIdx.x;
  const int tid = threadIdx.x;
  float acc[Ec];
#pragma unroll
  for (int e = 0; e < Ec; ++e) acc[e] = 0.f;
  const float* xr = x + (size_t)t * Hc;
  for (int h = tid; h < Hc; h += 256) {
    const float xv = xr[h];
    const float* w = rw + (size_t)h * Ec;
#pragma unroll
    for (int e = 0; e < Ec; ++e) acc[e] += xv * w[e];
  }
  __shared__ float red[256][Ec];
#pragma unroll
  for (int e = 0; e < Ec; ++e) red[tid][e] = acc[e];
  __syncthreads();
  for (int s = 128; s > 0; s >>= 1) {
    if (tid < s) {
#pragma unroll
      for (int e = 0; e < Ec; ++e) red[tid][e] += red[tid + s][e];
    }
    __syncthreads();
  }
  if (tid < Ec) logits[(size_t)t * Ec + tid] = red[0][tid];
}

// ---------------- top-2 ----------------
__global__ void topk_kernel(const float* __restrict__ logits, int* __restrict__ cnt,
                            int* __restrict__ tokList, float* __restrict__ wList) {
  const int t = blockIdx.x * blockDim.x + threadIdx.x;
  if (t >= Tc) return;
  float l[Ec];
#pragma unroll
  for (int e = 0; e < Ec; ++e) l[e] = logits[(size_t)t * Ec + e];
  float b0 = -3.4e38f, b1 = -3.4e38f;
  int i0 = 0, i1 = 0;
#pragma unroll
  for (int e = 0; e < Ec; ++e) {
    if (l[e] > b0) { b1 = b0; i1 = i0; b0 = l[e]; i0 = e; }
    else if (l[e] > b1) { b1 = l[e]; i1 = e; }
  }
  const float w0 = 1.f / (1.f + expf(b1 - b0));
  const float w1 = 1.f - w0;
  int p0 = atomicAdd(&cnt[i0], 1);
  tokList[i0 * Tc + p0] = t;
  wList[i0 * Tc + p0] = w0;
  int p1 = atomicAdd(&cnt[i1], 1);
  tokList[i1 * Tc + p1] = t;
  wList[i1 * Tc + p1] = w1;
}

__global__ void offsets_kernel(const int* __restrict__ cnt, int* __restrict__ off) {
  if (threadIdx.x == 0) {
    int s = 0;
    for (int e = 0; e < Ec; ++e) { off[e] = s; s += cnt[e]; }
  }
}

// ---------------- fp32 -> (hi,lo) bf16 split for activations ----------------
__global__ void convert_kernel(const float* __restrict__ x, unsigned short* __restrict__ xh,
                               unsigned short* __restrict__ xl) {
  const int i = blockIdx.x * 256 + threadIdx.x;
  const float v = x[i];
  const unsigned short h = f2bf(v);
  xh[i] = h;
  xl[i] = f2bf(v - bf2f(h));
}

// ---------------- weight convert into STAGED-TILE order ----------------
// fp32 [E][K][N] -> bf16 staged [e][nb=N/64][ks=K/32][q=4][n=64][j=8]; chunk = 4KB.
template <bool SPLIT>
__global__ __launch_bounds__(256) void wconv_kernel(const float* __restrict__ src,
                                                    unsigned short* __restrict__ dh,
                                                    unsigned short* __restrict__ dl,
                                                    int K, int N) {
  const int e = blockIdx.z;
  const int n0 = blockIdx.x * 64;
  const int k0 = blockIdx.y * 64;
  const int NB = N >> 6, KS = K >> 5;
  src += (size_t)e * K * N;

  __shared__ unsigned short lh[64][66];
  __shared__ unsigned short ll[SPLIT ? 64 : 1][66];
  const int tid = threadIdx.x;

  {
    const int r = tid >> 2, cg = (tid & 3) * 16;
    const float* sp = src + (size_t)(k0 + r) * N + n0 + cg;
#pragma unroll
    for (int i = 0; i < 16; i += 4) {
      const float4 v = *(const float4*)(sp + i);
      const float f[4] = {v.x, v.y, v.z, v.w};
#pragma unroll
      for (int j = 0; j < 4; ++j) {
        const unsigned short h = f2bf(f[j]);
        lh[r][cg + i + j] = h;
        if constexpr (SPLIT) ll[r][cg + i + j] = f2bf(f[j] - bf2f(h));
      }
    }
  }
  __syncthreads();
  {
    const int ksl = tid >> 7, q = (tid >> 5) & 3, n2 = (tid & 31) * 2;
    const int kb = ksl * 32 + q * 8;
    union { unsigned short s[16]; uint4 u[2]; } oh, ol;
#pragma unroll
    for (int s = 0; s < 2; ++s)
#pragma unroll
      for (int i = 0; i < 8; ++i) {
        oh.s[s * 8 + i] = lh[kb + i][n2 + s];
        if constexpr (SPLIT) ol.s[s * 8 + i] = ll[kb + i][n2 + s];
      }
    const size_t cb =
        (((size_t)e * NB + (n0 >> 6)) * KS + (k0 >> 5) + ksl) * 2048 + q * 512 + n2 * 8;
    *(uint4*)(dh + cb) = oh.u[0];
    *(uint4*)(dh + cb + 8) = oh.u[1];
    if constexpr (SPLIT) {
      *(uint4*)(dl + cb) = ol.u[0];
      *(uint4*)(dl + cb + 8) = ol.u[1];
    }
  }
}

// ---------------- gate_up GEMM: BM=128, BN=64(g)+64(u), BK=32, 2-phase dbuf ----------------
template <bool SPLIT>
__global__ __launch_bounds__(256) void gateup_kernel(
    const unsigned short* __restrict__ xh, const unsigned short* __restrict__ xl,
    const unsigned short* __restrict__ gwSh, const unsigned short* __restrict__ gwSl,
    const int* __restrict__ cnt, const int* __restrict__ off,
    const int* __restrict__ tokList, unsigned short* __restrict__ actH,
    unsigned short* __restrict__ actL) {
  // bijective chunked XCD swizzle: mi fastest, e middle, nb slowest (grid % 8 == 0)
  const int d = blockIdx.x;
  const int lid = (d & 7) * ((int)gridDim.x >> 3) + (d >> 3);
  const int mi = lid & 15;
  const int e = (lid >> 4) & 7;
  const int nb = lid >> 7;  // 0..31
  const int M = cnt[e];
  const int m0 = mi * 128;
  if (m0 >= M) return;
  const int tid = threadIdx.x;
  const int wv = tid >> 6, l64 = tid & 63;
  const int q = l64 >> 4, mr = l64 & 15;
  const int nc = wv * 16 + mr;
  const int wvo = wv * 1024;  // byte offset of wave's 1KB within a 4KB chunk

  __shared__ __align__(16) unsigned short sAh[2][128 * 40];
  __shared__ __align__(16) unsigned short sAl[2][SPLIT ? 128 * 40 : 8];
  __shared__ __align__(16) unsigned short sBgh[2][2048];
  __shared__ __align__(16) unsigned short sBgl[2][SPLIT ? 2048 : 8];
  __shared__ __align__(16) unsigned short sBuh[2][2048];
  __shared__ __align__(16) unsigned short sBul[2][SPLIT ? 2048 : 8];

  const size_t gBase = (((size_t)e * 64 + nb) * 32) * 2048 + tid * 8;
  const size_t uBase = (((size_t)e * 64 + nb + 32) * 32) * 2048 + tid * 8;

  const int ar = tid >> 2, ak = (tid & 3) * 8;
  int r0 = m0 + ar;      if (r0 >= M) r0 = M - 1;
  int r1 = m0 + 64 + ar; if (r1 >= M) r1 = M - 1;
  const size_t a0o = (size_t)tokList[e * Tc + r0] * Hc + ak;
  const size_t a1o = (size_t)tokList[e * Tc + r1] * Hc + ak;

  f32x4 accg[8], accu[8];
#pragma unroll
  for (int i = 0; i < 8; ++i) {
    accg[i] = f32x4{0.f, 0.f, 0.f, 0.f};
    accu[i] = f32x4{0.f, 0.f, 0.f, 0.f};
  }

  uint4 p0h = *(const uint4*)(xh + a0o);
  uint4 p1h = *(const uint4*)(xh + a1o);
  uint4 p0l, p1l;
  if constexpr (SPLIT) {
    p0l = *(const uint4*)(xl + a0o);
    p1l = *(const uint4*)(xl + a1o);
  }
  // prologue: stage buffer 0 (k-step 0), prefetch A @k=32
  *(uint4*)&sAh[0][ar * 40 + ak] = p0h;
  *(uint4*)&sAh[0][(ar + 64) * 40 + ak] = p1h;
  if constexpr (SPLIT) {
    *(uint4*)&sAl[0][ar * 40 + ak] = p0l;
    *(uint4*)&sAl[0][(ar + 64) * 40 + ak] = p1l;
  }
  gl2lds(gwSh + gBase, (char*)sBgh[0] + wvo);
  gl2lds(gwSh + uBase, (char*)sBuh[0] + wvo);
  if constexpr (SPLIT) {
    gl2lds(gwSl + gBase, (char*)sBgl[0] + wvo);
    gl2lds(gwSl + uBase, (char*)sBul[0] + wvo);
  }
  p0h = *(const uint4*)(xh + a0o + 32);
  p1h = *(const uint4*)(xh + a1o + 32);
  if constexpr (SPLIT) {
    p0l = *(const uint4*)(xl + a0o + 32);
    p1l = *(const uint4*)(xl + a1o + 32);
  }
  __syncthreads();

#define GU_STEP(CU, NX, KS)                                                           \
  {                                                                                   \
    if ((KS) + 1 < 32) {                                                              \
      gl2lds(gwSh + gBase + (size_t)((KS) + 1) * 2048, (char*)sBgh[NX] + wvo);        \
      gl2lds(gwSh + uBase + (size_t)((KS) + 1) * 2048, (char*)sBuh[NX] + wvo);        \
      if constexpr (SPLIT) {                                                          \
        gl2lds(gwSl + gBase + (size_t)((KS) + 1) * 2048, (char*)sBgl[NX] + wvo);      \
        gl2lds(gwSl + uBase + (size_t)((KS) + 1) * 2048, (char*)sBul[NX] + wvo);      \
      }                                                                               \
      *(uint4*)&sAh[NX][ar * 40 + ak] = p0h;                                          \
      *(uint4*)&sAh[NX][(ar + 64) * 40 + ak] = p1h;                                   \
      if constexpr (SPLIT) {                                                          \
        *(uint4*)&sAl[NX][ar * 40 + ak] = p0l;                                        \
        *(uint4*)&sAl[NX][(ar + 64) * 40 + ak] = p1l;                                 \
      }                                                                               \
      if ((KS) + 2 < 32) {                                                            \
        const int ko = ((KS) + 2) * 32;                                               \
        p0h = *(const uint4*)(xh + a0o + ko);                                         \
        p1h = *(const uint4*)(xh + a1o + ko);                                         \
        if constexpr (SPLIT) {                                                        \
          p0l = *(const uint4*)(xl + a0o + ko);                                       \
          p1l = *(const uint4*)(xl + a1o + ko);                                       \
        }                                                                             \
      }                                                                               \
    }                                                                                 \
    const bf16x8 bghf = ldfrag(&sBgh[CU][(q * 64 + nc) * 8]);                         \
    const bf16x8 buhf = ldfrag(&sBuh[CU][(q * 64 + nc) * 8]);                         \
    bf16x8 bglf, bulf;                                                                \
    if constexpr (SPLIT) {                                                            \
      bglf = ldfrag(&sBgl[CU][(q * 64 + nc) * 8]);                                    \
      bulf = ldfrag(&sBul[CU][(q * 64 + nc) * 8]);                                    \
    }                                                                                 \
    _Pragma("unroll")                                                                 \
    for (int mt = 0; mt < 8; ++mt) {                                                  \
      const bf16x8 ah = ldfrag(&sAh[CU][(mt * 16 + mr) * 40 + q * 8]);                \
      accg[mt] = __builtin_amdgcn_mfma_f32_16x16x32_bf16(ah, bghf, accg[mt], 0, 0, 0);\
      accu[mt] = __builtin_amdgcn_mfma_f32_16x16x32_bf16(ah, buhf, accu[mt], 0, 0, 0);\
      if constexpr (SPLIT) {                                                          \
        const bf16x8 alr = ldfrag(&sAl[CU][(mt * 16 + mr) * 40 + q * 8]);             \
        accg[mt] = __builtin_amdgcn_mfma_f32_16x16x32_bf16(ah, bglf, accg[mt], 0, 0, 0);\
        accg[mt] = __builtin_amdgcn_mfma_f32_16x16x32_bf16(alr, bghf, accg[mt], 0, 0, 0);\
        accu[mt] = __builtin_amdgcn_mfma_f32_16x16x32_bf16(ah, bulf, accu[mt], 0, 0, 0);\
        accu[mt] = __builtin_amdgcn_mfma_f32_16x16x32_bf16(alr, buhf, accu[mt], 0, 0, 0);\
      }                                                                               \
    }                                                                                 \
    __syncthreads();                                                                  \
  }

  for (int ks = 0; ks < 32; ks += 2) {
    GU_STEP(0, 1, ks)
    GU_STEP(1, 0, ks + 1)
  }
#undef GU_STEP

  const int valid = M - m0;
  const int rowbase = off[e] + m0;
#pragma unroll
  for (int mt = 0; mt < 8; ++mt) {
#pragma unroll
    for (int r = 0; r < 4; ++r) {
      const int row = mt * 16 + q * 4 + r;  // C/D: row=(lane>>4)*4+reg, col=lane&15 (m89)
      if (row < valid) {
        const float g = accg[mt][r];
        const float u = accu[mt][r];
        const float a = (g / (1.f + expf(-g))) * u;
        const size_t idx = (size_t)(rowbase + row) * Ic + (nb * 64 + nc);
        const unsigned short h = f2bf(a);
        actH[idx] = h;
        if constexpr (SPLIT) actL[idx] = f2bf(a - bf2f(h));
      }
    }
  }
}

// ---------------- down GEMM: BM=128, BN=64, K=Ic, 2-phase dbuf ----------------
template <bool SPLIT>
__global__ __launch_bounds__(256) void down_kernel(
    const unsigned short* __restrict__ actH, const unsigned short* __restrict__ actL,
    const unsigned short* __restrict__ dwSh, const unsigned short* __restrict__ dwSl,
    const int* __restrict__ cnt, const int* __restrict__ off,
    const int* __restrict__ tokList, const float* __restrict__ wList,
    float* __restrict__ out) {
  const int d = blockIdx.x;
  const int lid = (d & 7) * ((int)gridDim.x >> 3) + (d >> 3);
  const int mi = lid & 15;
  const int e = (lid >> 4) & 7;
  const int nb = lid >> 7;  // 0..15
  const int M = cnt[e];
  const int m0 = mi * 128;
  if (m0 >= M) return;
  const int tid = threadIdx.x;
  const int wv = tid >> 6, l64 = tid & 63;
  const int q = l64 >> 4, mr = l64 & 15;
  const int nc = wv * 16 + mr;
  const int wvo = wv * 1024;

  __shared__ __align__(16) unsigned short sAh[2][128 * 40];
  __shared__ __align__(16) unsigned short sAl[2][SPLIT ? 128 * 40 : 8];
  __shared__ __align__(16) unsigned short sBh[2][2048];
  __shared__ __align__(16) unsigned short sBl[2][SPLIT ? 2048 : 8];
  __shared__ int sTok[128];
  __shared__ float sW[128];

  if (tid < 128) {
    int r = m0 + tid;
    int rc = r < M ? r : M - 1;
    sTok[tid] = tokList[e * Tc + rc];
    sW[tid] = wList[e * Tc + rc];
  }

  const size_t bBase = (((size_t)e * 16 + nb) * 64) * 2048 + tid * 8;

  const int ar = tid >> 2, ak = (tid & 3) * 8;
  int r0 = m0 + ar;      if (r0 >= M) r0 = M - 1;
  int r1 = m0 + 64 + ar; if (r1 >= M) r1 = M - 1;
  const size_t a0o = (size_t)(off[e] + r0) * Ic + ak;
  const size_t a1o = (size_t)(off[e] + r1) * Ic + ak;

  f32x4 acc[8];
#pragma unroll
  for (int i = 0; i < 8; ++i) acc[i] = f32x4{0.f, 0.f, 0.f, 0.f};

  uint4 p0h = *(const uint4*)(actH + a0o);
  uint4 p1h = *(const uint4*)(actH + a1o);
  uint4 p0l, p1l;
  if constexpr (SPLIT) {
    p0l = *(const uint4*)(actL + a0o);
    p1l = *(const uint4*)(actL + a1o);
  }
  *(uint4*)&sAh[0][ar * 40 + ak] = p0h;
  *(uint4*)&sAh[0][(ar + 64) * 40 + ak] = p1h;
  if constexpr (SPLIT) {
    *(uint4*)&sAl[0][ar * 40 + ak] = p0l;
    *(uint4*)&sAl[0][(ar + 64) * 40 + ak] = p1l;
  }
  gl2lds(dwSh + bBase, (char*)sBh[0] + wvo);
  if constexpr (SPLIT) gl2lds(dwSl + bBase, (char*)sBl[0] + wvo);
  p0h = *(const uint4*)(actH + a0o + 32);
  p1h = *(const uint4*)(actH + a1o + 32);
  if constexpr (SPLIT) {
    p0l = *(const uint4*)(actL + a0o + 32);
    p1l = *(const uint4*)(actL + a1o + 32);
  }
  __syncthreads();

#define DN_STEP(CU, NX, KS)                                                           \
  {                                                                                   \
    if ((KS) + 1 < 64) {                                                              \
      gl2lds(dwSh + bBase + (size_t)((KS) + 1) * 2048, (char*)sBh[NX] + wvo);         \
      if constexpr (SPLIT)                                                            \
        gl2lds(dwSl + bBase + (size_t)((KS) + 1) * 2048, (char*)sBl[NX] + wvo);       \
      *(uint4*)&sAh[NX][ar * 40 + ak] = p0h;                                          \
      *(uint4*)&sAh[NX][(ar + 64) * 40 + ak] = p1h;                                   \
      if constexpr (SPLIT) {                                                          \
        *(uint4*)&sAl[NX][ar * 40 + ak] = p0l;                                        \
        *(uint4*)&sAl[NX][(ar + 64) * 40 + ak] = p1l;                                 \
      }                                                                               \
      if ((KS) + 2 < 64) {                                                            \
        const int ko = ((KS) + 2) * 32;                                               \
        p0h = *(const uint4*)(actH + a0o + ko);                                       \
        p1h = *(const uint4*)(actH + a1o + ko);                                       \
        if constexpr (SPLIT) {                                                        \
          p0l = *(const uint4*)(actL + a0o + ko);                                     \
          p1l = *(const uint4*)(actL + a1o + ko);                                     \
        }                                                                             \
      }                                                                               \
    }                                                                                 \
    const bf16x8 bh = ldfrag(&sBh[CU][(q * 64 + nc) * 8]);                            \
    bf16x8 bl;                                                                        \
    if constexpr (SPLIT) bl = ldfrag(&sBl[CU][(q * 64 + nc) * 8]);                    \
    _Pragma("unroll")                                                                 \
    for (int mt = 0; mt < 8; ++mt) {                                                  \
      const bf16x8 ah = ldfrag(&sAh[CU][(mt * 16 + mr) * 40 + q * 8]);                \
      acc[mt] = __builtin_amdgcn_mfma_f32_16x16x32_bf16(ah, bh, acc[mt], 0, 0, 0);    \
      if constexpr (SPLIT) {                                                          \
        const bf16x8 alr = ldfrag(&sAl[CU][(mt * 16 + mr) * 40 + q * 8]);             \
        acc[mt] = __builtin_amdgcn_mfma_f32_16x16x32_bf16(ah, bl, acc[mt], 0, 0, 0);  \
        acc[mt] = __builtin_amdgcn_mfma_f32_16x16x32_bf16(alr, bh, acc[mt], 0, 0, 0); \
      }                                                                               \
    }                                                                                 \
    __syncthreads();                                                                  \
  }

  for (int ks = 0; ks < 64; ks += 2) {
    DN_STEP(0, 1, ks)
    DN_STEP(1, 0, ks + 1)
  }
#undef DN_STEP

  const int valid = M - m0;
#pragma unroll
  for (int mt = 0; mt < 8; ++mt) {
#pragma unroll
    for (int r = 0; r < 4; ++r) {
      const int row = mt * 16 + q * 4 + r;
      if (row < valid) {
        atomicAdd(&out[(size_t)sTok[row] * Hc + (nb * 64 + nc)], sW[row] * acc[mt][r]);
      }
    }
  }
}

// ---------------- host ----------------
extern "C" void kernel_launch(void* const* d_in, const int* in_sizes, int n_in, void* d_out,
                              int out_size, void* d_ws, size_t ws_size, hipStream_t stream) {
  const float* x_in = (const float*)d_in[0];
  const float* rw = (const float*)d_in[1];
  const float* guw = (const float*)d_in[2];
  const float* dnw = (const float*)d_in[3];
  float* out = (float*)d_out;
  float* logits_base = out + (size_t)Tc * Hc;

  uint8_t* w = (uint8_t*)d_ws;
  float* x1 = (float*)w;                    w += (size_t)Tc * Hc * 4;
  unsigned short* xh = (unsigned short*)w;  w += (size_t)Tc * Hc * 2;
  unsigned short* xl = (unsigned short*)w;  w += (size_t)Tc * Hc * 2;
  unsigned short* actH = (unsigned short*)w; w += (size_t)Tc * 2 * Ic * 2;
  unsigned short* actL = (unsigned short*)w; w += (size_t)Tc * 2 * Ic * 2;
  int* tokList = (int*)w;                   w += (size_t)Ec * Tc * 4;
  float* wList = (float*)w;                 w += (size_t)Ec * Tc * 4;
  int* cnt0 = (int*)w;                      w += 64;
  int* cnt1 = (int*)w;                      w += 64;
  int* off = (int*)w;                       w += 64;
  unsigned short* wTh = (unsigned short*)w; w += (size_t)Ec * 2 * Ic * Hc * 2;
  unsigned short* wTl = (unsigned short*)w; w += (size_t)Ec * 2 * Ic * Hc * 2;

  hipMemsetAsync(cnt0, 0, 192, stream);
  hipMemsetAsync(x1, 0, (size_t)Tc * Hc * 4, stream);
  hipMemsetAsync(out, 0, (size_t)Tc * Hc * 4, stream);

  // ---- layer 0 (split-bf16 precision) ----
  router_kernel<<<Tc, 256, 0, stream>>>(x_in, rw, logits_base);
  topk_kernel<<<Tc / 256, 256, 0, stream>>>(logits_base, cnt0, tokList, wList);
  offsets_kernel<<<1, 64, 0, stream>>>(cnt0, off);
  convert_kernel<<<(Tc * Hc) / 256, 256, 0, stream>>>(x_in, xh, xl);
  wconv_kernel<true><<<dim3(2 * Ic / 64, Hc / 64, Ec), 256, 0, stream>>>(guw, wTh, wTl, Hc, 2 * Ic);
  gateup_kernel<true><<<16 * 32 * Ec, 256, 0, stream>>>(xh, xl, wTh, wTl, cnt0, off,
                                                        tokList, actH, actL);
  wconv_kernel<true><<<dim3(Hc / 64, Ic / 64, Ec), 256, 0, stream>>>(dnw, wTh, wTl, Ic, Hc);
  down_kernel<true><<<16 * 16 * Ec, 256, 0, stream>>>(actH, actL, wTh, wTl, cnt0,
                                                      off, tokList, wList, x1);

  // ---- layer 1 (plain bf16) ----
  const float* rw1 = rw + (size_t)Hc * Ec;
  const float* guw1 = guw + (size_t)Ec * Hc * 2 * Ic;
  const float* dnw1 = dnw + (size_t)Ec * Ic * Hc;
  router_kernel<<<Tc, 256, 0, stream>>>(x1, rw1, logits_base + (size_t)Tc * Ec);
  topk_kernel<<<Tc / 256, 256, 0, stream>>>(logits_base + (size_t)Tc * Ec, cnt1, tokList, wList);
  offsets_kernel<<<1, 64, 0, stream>>>(cnt1, off);
  convert_kernel<<<(Tc * Hc) / 256, 256, 0, stream>>>(x1, xh, xl);
  wconv_kernel<false><<<dim3(2 * Ic / 64, Hc / 64, Ec), 256, 0, stream>>>(guw1, wTh, wTl, Hc, 2 * Ic);
  gateup_kernel<false><<<16 * 32 * Ec, 256, 0, stream>>>(xh, xl, wTh, wTl, cnt1, off,
                                                         tokList, actH, actL);
  wconv_kernel<false><<<dim3(Hc / 64, Ic / 64, Ec), 256, 0, stream>>>(dnw1, wTh, wTl, Ic, Hc);
  down_kernel<false><<<16 * 16 * Ec, 256, 0, stream>>>(actH, actL, wTh, wTl, cnt1,
                                                       off, tokList, wList, out);
}